// Round 7
// baseline (473.589 us; speedup 1.0000x reference)
//
#include <hip/hip_runtime.h>
#include <math.h>

// Problem constants (fixed by the reference)
#define N_NODES 1024
#define BATCH   8
#define FEAT    128        // F == O
#define NDIR    3
#define NB      (N_NODES*BATCH)   // 8192
#define G3      384               // 3*O

typedef __bf16 bf16_t;
using bf16x8 = __attribute__((ext_vector_type(8))) __bf16;
using bf16x4 = __attribute__((ext_vector_type(4))) __bf16;
using f32x4  = __attribute__((ext_vector_type(4))) float;

// async global->LDS 16B per lane; LDS dest must be wave-uniform base (+lane*16)
#define GLOAD_LDS16(g, l) \
    __builtin_amdgcn_global_load_lds((const __attribute__((address_space(1))) void*)(g), \
                                     (__attribute__((address_space(3))) void*)(l), 16, 0, 0)

// ---------------------------------------------------------------------------
// 64x64-tile, BK=64 MFMA helpers (round-5 proven structure).
// ---------------------------------------------------------------------------
#define STAGE64(As, Bs, Arow, Brow, sA, sB, k0, w, lane)                      \
    {                                                                          \
        _Pragma("unroll")                                                      \
        for (int q = 0; q < 2; ++q) {                                          \
            int qq = (w)*2 + q;                                                \
            int row = qq*8 + ((lane) >> 3), seg = (lane) & 7;                  \
            GLOAD_LDS16((Arow) + (size_t)row*(sA) + (k0) + seg*8,              \
                        (char*)(As) + qq*1024);                                \
            GLOAD_LDS16((Brow) + (size_t)row*(sB) + (k0) + seg*8,              \
                        (char*)(Bs) + qq*1024);                                \
        }                                                                      \
    }

#define MFMA64(As, Bs, acc, w, lane)                                           \
    {                                                                          \
        _Pragma("unroll")                                                      \
        for (int ks = 0; ks < 64; ks += 32) {                                  \
            bf16x8 af = *reinterpret_cast<const bf16x8*>(                      \
                &(As)[((w)*16 + ((lane) & 15))*64 + ks + (((lane) >> 4) * 8)]);\
            _Pragma("unroll")                                                  \
            for (int j = 0; j < 4; ++j) {                                      \
                bf16x8 bfv = *reinterpret_cast<const bf16x8*>(                 \
                    &(Bs)[(j*16 + ((lane) & 15))*64 + ks + (((lane) >> 4) * 8)]);\
                (acc)[j] = __builtin_amdgcn_mfma_f32_16x16x32_bf16(af, bfv, (acc)[j], 0, 0, 0); \
            }                                                                  \
        }                                                                      \
    }

// ---------------------------------------------------------------------------
// adj fp32 -> CENTERED bf16 (adj - 0.5)
// ---------------------------------------------------------------------------
__global__ __launch_bounds__(256) void k_cvt_adj(
    const float* __restrict__ src, bf16_t* __restrict__ dst, int n4)
{
    int i = blockIdx.x * 256 + threadIdx.x;
    int stride = gridDim.x * 256;
    for (; i < n4; i += stride) {
        float4 v = reinterpret_cast<const float4*>(src)[i];
        bf16x4 o;
        o[0] = (bf16_t)(v.x - 0.5f); o[1] = (bf16_t)(v.y - 0.5f);
        o[2] = (bf16_t)(v.z - 0.5f); o[3] = (bf16_t)(v.w - 0.5f);
        *reinterpret_cast<bf16x4*>(&dst[(size_t)i * 4]) = o;
    }
}

// ---------------------------------------------------------------------------
// Weight prep, hi/lo split concats (K'=384):
//  m<384: W -> wsup (pattern A [hi|lo|hi]); m in [384,512): Wh -> wsup (A)
//  m in [512,896): Whh -> whhc (A);  m in [896,1280): Wih -> wihc (B [hi|hi|lo])
// ---------------------------------------------------------------------------
__global__ __launch_bounds__(128) void k_wprep(
    const float* __restrict__ W, const float* __restrict__ Wh,
    const float* __restrict__ Whh, const float* __restrict__ Wih,
    bf16_t* __restrict__ wsup,    // [2][512][384]
    bf16_t* __restrict__ whhc,    // [2][384][384]
    bf16_t* __restrict__ wihc)    // [2][384][384]
{
    int m = blockIdx.x, l = blockIdx.y, k = threadIdx.x;
    float w;
    bf16_t* dst;
    bool patB = false;
    if (m < 384) {
        int d = m >> 7, o = m & 127;
        w = W[((size_t)(l*3 + d)*128 + k)*128 + o];
        dst = wsup + ((size_t)l*512 + m)*384;
    } else if (m < 512) {
        int o = m - 384;
        w = Wh[((size_t)l*128 + k)*128 + o];
        dst = wsup + ((size_t)l*512 + m)*384;
    } else if (m < 896) {
        int c = m - 512;
        w = Whh[((size_t)l*384 + c)*128 + k];
        dst = whhc + ((size_t)l*384 + c)*384;
    } else {
        int c = m - 896;
        w = Wih[((size_t)l*384 + c)*128 + k];
        dst = wihc + ((size_t)l*384 + c)*384;
        patB = true;
    }
    bf16_t hi = (bf16_t)w;
    bf16_t lo = (bf16_t)(w - (float)hi);
    if (patB) { dst[k] = hi; dst[128 + k] = hi; dst[256 + k] = lo; }
    else      { dst[k] = hi; dst[128 + k] = lo; dst[256 + k] = hi; }
}

// ---------------------------------------------------------------------------
// x-cat build (layer 0): inputs fp32 [N,B,128] -> xcat [8][1024][384] = [hi|hi|lo]
// ---------------------------------------------------------------------------
__global__ __launch_bounds__(256) void k_xcat(
    const float* __restrict__ X, bf16_t* __restrict__ xcat)
{
    int idx = blockIdx.x * 256 + threadIdx.x;   // over 8192*128
    int k = idx & 127, r = idx >> 7;
    int n = r >> 3, b = r & 7;
    float v = X[idx];
    bf16_t hi = (bf16_t)v;
    bf16_t lo = (bf16_t)(v - (float)hi);
    bf16_t* dst = xcat + ((size_t)(b*1024 + n))*384 + k;
    dst[0] = hi; dst[128] = hi; dst[256] = lo;
}

// ---------------------------------------------------------------------------
// xsum prep: xsum[0][b][o] = sum_n inputs[n][b][o] (fp32); zero xsum[1].
// grid 8 (b), 256 threads.
// ---------------------------------------------------------------------------
__global__ __launch_bounds__(256) void k_xsum0(
    const float* __restrict__ X, float* __restrict__ xsum)
{
    __shared__ float red[256];
    int b = blockIdx.x, t = threadIdx.x;
    int o = t & 127, h = t >> 7;
    float s = 0.0f;
    for (int n = h; n < 1024; n += 2)
        s += X[(size_t)(n*8 + b)*128 + o];
    red[t] = s;
    __syncthreads();
    if (t < 128) {
        xsum[b*128 + t] = red[t] + red[t + 128];
        xsum[1024 + b*128 + t] = 0.0f;      // zero layer-1 accumulator
    }
}

// ---------------------------------------------------------------------------
// Fused sup + gh GEMM (both K'=384, 64x64, BK=64). 1D grid of 1792 blocks:
//  id < 1024: sup tile  (n-tile = id&15, m-tile = (id>>4)&7, b = id>>7)
//    m<384 : supt[((m>>7)*8+b)*128+(m&127)][n] = bf16(C + Bc)
//    m>=384: tbuf[(b*128+m-384)][n] = relu(C + Bh)
//  id >= 1024: gh tile (m-tile = g&127, c-tile = g>>7)
//    ghb[m][c] = bf16(C + bhh[c])
// ---------------------------------------------------------------------------
__global__ __launch_bounds__(256, 4) void k_supgh(
    const bf16_t* __restrict__ Wcat,  // [512][384]
    const bf16_t* __restrict__ xcat,  // [8][1024][384]
    const bf16_t* __restrict__ whhc,  // [384][384]
    const float* __restrict__ Bcl,    // [3,128]
    const float* __restrict__ Bhl,    // [128]
    const float* __restrict__ bhh,    // [384]
    bf16_t* __restrict__ supt,        // [24][128][1024]
    float* __restrict__ tbuf,         // [8][128][1024]
    bf16_t* __restrict__ ghb)         // [8192][384]
{
    __shared__ bf16_t As[64*64];
    __shared__ bf16_t Bs[64*64];
    const int t = threadIdx.x, lane = t & 63, w = t >> 6;
    const int id = blockIdx.x;
    const bf16_t *Arow, *Brow;
    int m0, n0 = 0, b = 0, c0 = 0;
    if (id < 1024) {
        n0 = (id & 15) * 64; m0 = ((id >> 4) & 7) * 64; b = id >> 7;
        Arow = Wcat + (size_t)m0 * 384;
        Brow = xcat + ((size_t)b * 1024 + n0) * 384;
    } else {
        int g = id - 1024;
        m0 = (g & 127) * 64; c0 = (g >> 7) * 64;
        Arow = xcat + (size_t)m0 * 384;
        Brow = whhc + (size_t)c0 * 384;
    }

    f32x4 acc[4] = {};
    for (int k0 = 0; k0 < 384; k0 += 64) {
        STAGE64(As, Bs, Arow, Brow, 384, 384, k0, w, lane);
        __syncthreads();
        MFMA64(As, Bs, acc, w, lane);
        __syncthreads();
    }
    if (id < 1024) {
        #pragma unroll
        for (int j = 0; j < 4; ++j) {
            int n = n0 + j*16 + (lane & 15);
            #pragma unroll
            for (int rg = 0; rg < 4; ++rg) {
                int m = m0 + w*16 + (lane >> 4)*4 + rg;
                float v = acc[j][rg];
                if (m < 384) {
                    int d = m >> 7, o = m & 127;
                    supt[((size_t)((d*8 + b)*128 + o))*1024 + n] = (bf16_t)(v + Bcl[d*128 + o]);
                } else {
                    int o = m - 384;
                    tbuf[((size_t)(b*128 + o))*1024 + n] = fmaxf(v + Bhl[o], 0.0f);
                }
            }
        }
    } else {
        #pragma unroll
        for (int j = 0; j < 4; ++j) {
            int c = c0 + j*16 + (lane & 15);
            float bv = bhh[c];
            #pragma unroll
            for (int rg = 0; rg < 4; ++rg) {
                int m = m0 + w*16 + (lane >> 4)*4 + rg;
                ghb[(size_t)m*G3 + c] = (bf16_t)(acc[j][rg] + bv);
            }
        }
    }
}

// ---------------------------------------------------------------------------
// k_agg (64m x 128o per block, BK=64):
//   agg[z][m][o] = sum_n adjc[z][m][n]*supt[z][o][n] + 0.5*colsum[z][o]
// colsum computed analytically in the prologue (fp32 exact):
//   colsum[z][o] = xsum[b]·W[d][:,o] + 1024*Bc[d][o]
// Output aggcat [24576][384] = [hi|lo|hi]. grid (16 m-tiles, 24 z).
// ---------------------------------------------------------------------------
__global__ __launch_bounds__(256, 4) void k_agg(
    const bf16_t* __restrict__ adjb,   // [24][1024][1024] centered
    const bf16_t* __restrict__ supt,   // [24][128][1024]
    const float* __restrict__ xsum,    // [8][128] (this layer)
    const float* __restrict__ Wl,      // [3][128][128] fp32 (this layer)
    const float* __restrict__ Bcl,     // [3][128]
    bf16_t* __restrict__ aggcat)       // [24576][384]
{
    __shared__ bf16_t As[64*64];       // 8 KB
    __shared__ bf16_t Bs[128*64];      // 16 KB
    __shared__ float xs[128];
    __shared__ float red[256];
    __shared__ float cs_sh[128];
    const int t = threadIdx.x, lane = t & 63, w = t >> 6;
    const int m0 = blockIdx.x * 64;
    const int z  = blockIdx.y;
    const int b  = z & 7, d = z >> 3;

    // prologue: 0.5*colsum from xsum (exact w.r.t. fp32 support)
    if (t < 128) xs[t] = xsum[b*128 + t];
    __syncthreads();
    {
        int o = t & 127, h = t >> 7;
        float s = 0.0f;
        const float* Wd = Wl + (size_t)d*128*128;
        for (int k = h*64; k < h*64 + 64; ++k)
            s += xs[k] * Wd[k*128 + o];
        red[t] = s;
        __syncthreads();
        if (t < 128)
            cs_sh[t] = 0.5f*(red[t] + red[t+128]) + 512.0f*Bcl[d*128 + t];
        __syncthreads();
    }

    const bf16_t* Az = adjb + (size_t)z*1024*1024 + (size_t)m0*1024;
    const bf16_t* Bz = supt + (size_t)z*128*1024;

    f32x4 acc[8] = {};
    for (int k0 = 0; k0 < 1024; k0 += 64) {
        #pragma unroll
        for (int q = 0; q < 6; ++q) {
            int c = w*6 + q;                       // 24 chunks of 8 rows
            int rl = (lane >> 3), seg = (lane & 7)*8;
            if (c < 8)
                GLOAD_LDS16(Az + (size_t)(c*8 + rl)*1024 + k0 + seg,
                            (char*)As + c*1024);
            else
                GLOAD_LDS16(Bz + (size_t)((c-8)*8 + rl)*1024 + k0 + seg,
                            (char*)Bs + (c-8)*1024);
        }
        __syncthreads();
        #pragma unroll
        for (int ks = 0; ks < 64; ks += 32) {
            bf16x8 af = *reinterpret_cast<const bf16x8*>(
                &As[(w*16 + (lane & 15))*64 + ks + ((lane >> 4)*8)]);
            #pragma unroll
            for (int j = 0; j < 8; ++j) {
                bf16x8 bfv = *reinterpret_cast<const bf16x8*>(
                    &Bs[(j*16 + (lane & 15))*64 + ks + ((lane >> 4)*8)]);
                acc[j] = __builtin_amdgcn_mfma_f32_16x16x32_bf16(af, bfv, acc[j], 0, 0, 0);
            }
        }
        __syncthreads();
    }
    #pragma unroll
    for (int j = 0; j < 8; ++j) {
        int o = j*16 + (lane & 15);
        float cs = cs_sh[o];
        #pragma unroll
        for (int rg = 0; rg < 4; ++rg) {
            size_t m = (size_t)z*1024 + m0 + w*16 + (lane >> 4)*4 + rg;
            float v = acc[j][rg] + cs;
            bf16_t hi = (bf16_t)v;
            bf16_t lo = (bf16_t)(v - (float)hi);
            bf16_t* row = aggcat + m*384;
            row[o] = hi; row[128 + o] = lo; row[256 + o] = hi;
        }
    }
}

// ---------------------------------------------------------------------------
// k_gi (64x64, BK=64, K=384 hi/lo exact): gi[m][c] = aggcat·wihc + bih
// c<256 -> girz bf16; c>=256 -> gin fp32. grid (384 m-tiles, 6 c-tiles).
// ---------------------------------------------------------------------------
__global__ __launch_bounds__(256, 4) void k_gi(
    const bf16_t* __restrict__ A,      // [24576][384]
    const bf16_t* __restrict__ B,      // [384][384]
    const float*  __restrict__ bias,   // [384]
    bf16_t* __restrict__ girz,         // [24576][256]
    float* __restrict__ gin)           // [24576][128]
{
    __shared__ bf16_t As[64*64];
    __shared__ bf16_t Bs[64*64];
    const int t = threadIdx.x, lane = t & 63, w = t >> 6;
    const int m0 = blockIdx.x * 64;
    const int c0 = blockIdx.y * 64;
    const bf16_t* Arow = A + (size_t)m0 * 384;
    const bf16_t* Brow = B + (size_t)c0 * 384;

    f32x4 acc[4] = {};
    for (int k0 = 0; k0 < 384; k0 += 64) {
        STAGE64(As, Bs, Arow, Brow, 384, 384, k0, w, lane);
        __syncthreads();
        MFMA64(As, Bs, acc, w, lane);
        __syncthreads();
    }
    #pragma unroll
    for (int j = 0; j < 4; ++j) {
        int c = c0 + j*16 + (lane & 15);
        float bv = bias[c];
        #pragma unroll
        for (int rg = 0; rg < 4; ++rg) {
            int m = m0 + w*16 + (lane >> 4)*4 + rg;
            float v = acc[j][rg] + bv;
            if (c < 256) girz[(size_t)m*256 + c] = (bf16_t)v;
            else         gin[(size_t)m*128 + (c - 256)] = v;
        }
    }
}

// ---------------------------------------------------------------------------
// GRU gates + sum over d + relu + highway blend. h from xcat (hi+lo, exact).
// Optionally accumulates xsum_next[b][o] += sum_n res (for layer-1 colsum).
// grid (64 n-blocks of 16, 8 b), 256 threads.
// ---------------------------------------------------------------------------
__global__ __launch_bounds__(256) void k_gates(
    const bf16_t* __restrict__ girz, const float* __restrict__ gin,
    const bf16_t* __restrict__ ghb,
    bf16_t* xcat,                       // NOT restrict: read+write same buffer
    const float* __restrict__ tbuf,
    float* __restrict__ Xout, int write_xcat,
    float* __restrict__ xsum_next)
{
    __shared__ float ts[128*17];
    __shared__ float red[256];
    const int b = blockIdx.y, n0 = blockIdx.x * 16;
    const int tid = threadIdx.x;
    {
        int o = tid >> 1, nh = (tid & 1) * 8;
        const float* src = tbuf + ((size_t)(b*128 + o))*1024 + n0 + nh;
        float4 v0 = *reinterpret_cast<const float4*>(src);
        float4 v1 = *reinterpret_cast<const float4*>(src + 4);
        float* dst = &ts[o*17 + nh];
        dst[0]=v0.x; dst[1]=v0.y; dst[2]=v0.z; dst[3]=v0.w;
        dst[4]=v1.x; dst[5]=v1.y; dst[6]=v1.z; dst[7]=v1.w;
    }
    __syncthreads();
    float xacc = 0.0f;
    #pragma unroll
    for (int p = 0; p < 8; ++p) {
        int e = p*256 + tid;
        int nn = e >> 7, o = e & 127;
        int n = n0 + nn;
        size_t rb = (size_t)(b*1024 + n);
        bf16_t* xr = xcat + rb*384;
        float h = (float)xr[o] + (float)xr[256 + o];
        const bf16_t* ghr = ghb + rb*G3;
        float g_r = (float)ghr[o], g_z = (float)ghr[128+o], g_n = (float)ghr[256+o];
        float acc = 0.0f;
        #pragma unroll
        for (int d = 0; d < 3; ++d) {
            size_t rr = (size_t)((d*8 + b)*1024 + n);
            float i_r = (float)girz[rr*256 + o];
            float i_z = (float)girz[rr*256 + 128 + o];
            float i_n = gin[rr*128 + o];
            float rg = 1.0f / (1.0f + expf(-(i_r + g_r)));
            float zg = 1.0f / (1.0f + expf(-(i_z + g_z)));
            float ng = tanhf(i_n + rg * g_n);
            acc += (1.0f - zg) * ng + zg * h;
        }
        float outv = fmaxf(acc, 0.0f);
        float tg = ts[o*17 + nn];
        float res = outv * tg + h * (1.0f - tg);
        xacc += res;
        if (Xout) Xout[(size_t)(n*8 + b)*128 + o] = res;
        if (write_xcat) {
            bf16_t hi = (bf16_t)res;
            bf16_t lo = (bf16_t)(res - (float)hi);
            xr[o] = hi; xr[128 + o] = hi; xr[256 + o] = lo;
        }
    }
    if (xsum_next) {
        // thread tid and tid+128 share o = tid&127 (different n halves)
        red[tid] = xacc;
        __syncthreads();
        if (tid < 128)
            atomicAdd(xsum_next + b*128 + tid, red[tid] + red[tid + 128]);
    }
}

// ---------------------------------------------------------------------------
extern "C" void kernel_launch(void* const* d_in, const int* in_sizes, int n_in,
                              void* d_out, int out_size, void* d_ws, size_t ws_size,
                              hipStream_t stream) {
    const float* inputs = (const float*)d_in[0];   // [1024,8,128]
    const float* adj    = (const float*)d_in[1];   // [3,8,1024,1024]
    const float* W      = (const float*)d_in[2];   // [2,3,128,128]
    const float* Bc     = (const float*)d_in[3];   // [2,3,128]
    const float* Wh     = (const float*)d_in[4];   // [2,128,128]
    const float* Bh     = (const float*)d_in[5];   // [2,128]
    const float* Wih    = (const float*)d_in[6];   // [2,384,128]
    const float* Whh    = (const float*)d_in[7];   // [2,384,128]
    const float* bih    = (const float*)d_in[8];   // [2,384]
    const float* bhh    = (const float*)d_in[9];   // [2,384]

    char* ws = (char*)d_ws;
    float*  tbuf   = (float*)ws;   ws += (size_t)8*128*1024*4;      // 4.19 MB
    bf16_t* xcat   = (bf16_t*)ws;  ws += (size_t)8*1024*384*2;      // 6.29 MB
    bf16_t* ghb    = (bf16_t*)ws;  ws += (size_t)NB*G3*2;           // 6.29 MB
    bf16_t* supt   = (bf16_t*)ws;  ws += (size_t)24*128*1024*2;     // 6.29 MB
    bf16_t* aggcat = (bf16_t*)ws;  ws += (size_t)3*NB*384*2;        // 18.87 MB
    bf16_t* girz   = (bf16_t*)ws;  ws += (size_t)3*NB*256*2;        // 12.58 MB
    float*  gin    = (float*)ws;   ws += (size_t)3*NB*128*4;        // 12.58 MB
    float*  xsum   = (float*)ws;   ws += (size_t)2*8*128*4;         // 8 KB
    bf16_t* wsup   = (bf16_t*)ws;  ws += (size_t)2*512*384*2;       // 0.79 MB
    bf16_t* whhc   = (bf16_t*)ws;  ws += (size_t)2*384*384*2;       // 1.18 MB
    bf16_t* wihc   = (bf16_t*)ws;  ws += (size_t)2*384*384*2;       // 1.18 MB
    bf16_t* adjb   = (bf16_t*)ws;                                   // 50.33 MB

    // one-time preps
    k_cvt_adj<<<dim3(4096), dim3(256), 0, stream>>>(adj, adjb, 3*8*1024*1024/4);
    k_wprep<<<dim3(1280, 2), dim3(128), 0, stream>>>(W, Wh, Whh, Wih, wsup, whhc, wihc);
    k_xcat<<<dim3(4096), dim3(256), 0, stream>>>(inputs, xcat);
    k_xsum0<<<dim3(8), dim3(256), 0, stream>>>(inputs, xsum);

    for (int l = 0; l < 2; ++l) {
        // fused: support (bf16 [z][o][n]) + highway t (fp32 [b][o][n]) + gh
        k_supgh<<<dim3(1792), dim3(256), 0, stream>>>(
            wsup + (size_t)l*512*384, xcat, whhc + (size_t)l*384*384,
            Bc + l*3*128, Bh + l*128, bhh + l*G3, supt, tbuf, ghb);
        // agg = adjc @ support + 0.5*colsum(analytic), output hi/lo-cat
        k_agg<<<dim3(16, 24), dim3(256), 0, stream>>>(
            adjb, supt, xsum + l*1024, W + (size_t)l*3*128*128, Bc + l*3*128,
            aggcat);
        // gi = agg @ Wih^T + bih (K=384 hi/lo exact)
        k_gi<<<dim3(384, 6), dim3(256), 0, stream>>>(
            aggcat, wihc + (size_t)l*384*384, bih + l*G3, girz, gin);
        // gates + sum_d + relu + highway; layer0 -> xcat update + xsum1 accum
        k_gates<<<dim3(64, 8), dim3(256), 0, stream>>>(
            girz, gin, ghb, xcat, tbuf,
            (l == 1) ? (float*)d_out : (float*)nullptr, (l == 0) ? 1 : 0,
            (l == 0) ? (xsum + 1024) : (float*)nullptr);
    }
}

// Round 8
// 346.335 us; speedup vs baseline: 1.3674x; 1.3674x over previous
//
#include <hip/hip_runtime.h>
#include <math.h>

// Problem constants (fixed by the reference)
#define N_NODES 1024
#define BATCH   8
#define FEAT    128        // F == O
#define NDIR    3
#define NB      (N_NODES*BATCH)   // 8192
#define G3      384               // 3*O

typedef __bf16 bf16_t;
using bf16x8 = __attribute__((ext_vector_type(8))) __bf16;
using bf16x4 = __attribute__((ext_vector_type(4))) __bf16;
using f32x4  = __attribute__((ext_vector_type(4))) float;

// async global->LDS 16B per lane; LDS dest must be wave-uniform base (+lane*16)
#define GLOAD_LDS16(g, l) \
    __builtin_amdgcn_global_load_lds((const __attribute__((address_space(1))) void*)(g), \
                                     (__attribute__((address_space(3))) void*)(l), 16, 0, 0)

// ---------------------------------------------------------------------------
// 64x64-tile, BK=64 MFMA helpers (round-5 proven structure).
// ---------------------------------------------------------------------------
#define STAGE64(As, Bs, Arow, Brow, sA, sB, k0, w, lane)                      \
    {                                                                          \
        _Pragma("unroll")                                                      \
        for (int q = 0; q < 2; ++q) {                                          \
            int qq = (w)*2 + q;                                                \
            int row = qq*8 + ((lane) >> 3), seg = (lane) & 7;                  \
            GLOAD_LDS16((Arow) + (size_t)row*(sA) + (k0) + seg*8,              \
                        (char*)(As) + qq*1024);                                \
            GLOAD_LDS16((Brow) + (size_t)row*(sB) + (k0) + seg*8,              \
                        (char*)(Bs) + qq*1024);                                \
        }                                                                      \
    }

#define MFMA64(As, Bs, acc, w, lane)                                           \
    {                                                                          \
        _Pragma("unroll")                                                      \
        for (int ks = 0; ks < 64; ks += 32) {                                  \
            bf16x8 af = *reinterpret_cast<const bf16x8*>(                      \
                &(As)[((w)*16 + ((lane) & 15))*64 + ks + (((lane) >> 4) * 8)]);\
            _Pragma("unroll")                                                  \
            for (int j = 0; j < 4; ++j) {                                      \
                bf16x8 bfv = *reinterpret_cast<const bf16x8*>(                 \
                    &(Bs)[(j*16 + ((lane) & 15))*64 + ks + (((lane) >> 4) * 8)]);\
                (acc)[j] = __builtin_amdgcn_mfma_f32_16x16x32_bf16(af, bfv, (acc)[j], 0, 0, 0); \
            }                                                                  \
        }                                                                      \
    }

// ---------------------------------------------------------------------------
// adj fp32 -> CENTERED bf16 (adj - 0.5)
// ---------------------------------------------------------------------------
__global__ __launch_bounds__(256) void k_cvt_adj(
    const float* __restrict__ src, bf16_t* __restrict__ dst, int n4)
{
    int i = blockIdx.x * 256 + threadIdx.x;
    int stride = gridDim.x * 256;
    for (; i < n4; i += stride) {
        float4 v = reinterpret_cast<const float4*>(src)[i];
        bf16x4 o;
        o[0] = (bf16_t)(v.x - 0.5f); o[1] = (bf16_t)(v.y - 0.5f);
        o[2] = (bf16_t)(v.z - 0.5f); o[3] = (bf16_t)(v.w - 0.5f);
        *reinterpret_cast<bf16x4*>(&dst[(size_t)i * 4]) = o;
    }
}

// ---------------------------------------------------------------------------
// Weight prep, hi/lo split concats (K'=384):
//  m<384: W -> wsup (pattern A [hi|lo|hi]); m in [384,512): Wh -> wsup (A)
//  m in [512,896): Whh -> whhc (A);  m in [896,1280): Wih -> wihc (B [hi|hi|lo])
// ---------------------------------------------------------------------------
__global__ __launch_bounds__(128) void k_wprep(
    const float* __restrict__ W, const float* __restrict__ Wh,
    const float* __restrict__ Whh, const float* __restrict__ Wih,
    bf16_t* __restrict__ wsup,    // [2][512][384]
    bf16_t* __restrict__ whhc,    // [2][384][384]
    bf16_t* __restrict__ wihc)    // [2][384][384]
{
    int m = blockIdx.x, l = blockIdx.y, k = threadIdx.x;
    float w;
    bf16_t* dst;
    bool patB = false;
    if (m < 384) {
        int d = m >> 7, o = m & 127;
        w = W[((size_t)(l*3 + d)*128 + k)*128 + o];
        dst = wsup + ((size_t)l*512 + m)*384;
    } else if (m < 512) {
        int o = m - 384;
        w = Wh[((size_t)l*128 + k)*128 + o];
        dst = wsup + ((size_t)l*512 + m)*384;
    } else if (m < 896) {
        int c = m - 512;
        w = Whh[((size_t)l*384 + c)*128 + k];
        dst = whhc + ((size_t)l*384 + c)*384;
    } else {
        int c = m - 896;
        w = Wih[((size_t)l*384 + c)*128 + k];
        dst = wihc + ((size_t)l*384 + c)*384;
        patB = true;
    }
    bf16_t hi = (bf16_t)w;
    bf16_t lo = (bf16_t)(w - (float)hi);
    if (patB) { dst[k] = hi; dst[128 + k] = hi; dst[256 + k] = lo; }
    else      { dst[k] = hi; dst[128 + k] = lo; dst[256 + k] = hi; }
}

// ---------------------------------------------------------------------------
// x-cat build (layer 0): inputs fp32 [N,B,128] -> xcat [8][1024][384] = [hi|hi|lo]
// ---------------------------------------------------------------------------
__global__ __launch_bounds__(256) void k_xcat(
    const float* __restrict__ X, bf16_t* __restrict__ xcat)
{
    int idx = blockIdx.x * 256 + threadIdx.x;   // over 8192*128
    int k = idx & 127, r = idx >> 7;
    int n = r >> 3, b = r & 7;
    float v = X[idx];
    bf16_t hi = (bf16_t)v;
    bf16_t lo = (bf16_t)(v - (float)hi);
    bf16_t* dst = xcat + ((size_t)(b*1024 + n))*384 + k;
    dst[0] = hi; dst[128] = hi; dst[256] = lo;
}

// ---------------------------------------------------------------------------
// xsum0: xsum[0][b][o] += sum_n inputs[n][b][o]. grid (64,8), wide + atomics.
// xsum must be pre-zeroed (hipMemsetAsync).
// ---------------------------------------------------------------------------
__global__ __launch_bounds__(256) void k_xsum0(
    const float* __restrict__ X, float* __restrict__ xsum)
{
    __shared__ float red[256];
    int g = blockIdx.x, b = blockIdx.y;
    int t = threadIdx.x, o = t & 127, h = t >> 7;
    float s = 0.0f;
    #pragma unroll
    for (int i = 0; i < 8; ++i) {
        int n = g*16 + h*8 + i;
        s += X[(size_t)(n*8 + b)*128 + o];
    }
    red[t] = s;
    __syncthreads();
    if (t < 128) atomicAdd(xsum + b*128 + t, red[t] + red[t + 128]);
}

// ---------------------------------------------------------------------------
// Fused sup + gh GEMM (both K'=384, 64x64, BK=64). 1D grid of 1792 blocks:
//  id < 1024: sup tile; id >= 1024: gh tile.
// ---------------------------------------------------------------------------
__global__ __launch_bounds__(256, 4) void k_supgh(
    const bf16_t* __restrict__ Wcat,  // [512][384]
    const bf16_t* __restrict__ xcat,  // [8][1024][384]
    const bf16_t* __restrict__ whhc,  // [384][384]
    const float* __restrict__ Bcl,    // [3,128]
    const float* __restrict__ Bhl,    // [128]
    const float* __restrict__ bhh,    // [384]
    bf16_t* __restrict__ supt,        // [24][128][1024]
    float* __restrict__ tbuf,         // [8][128][1024]
    bf16_t* __restrict__ ghb)         // [8192][384]
{
    __shared__ bf16_t As[64*64];
    __shared__ bf16_t Bs[64*64];
    const int t = threadIdx.x, lane = t & 63, w = t >> 6;
    const int id = blockIdx.x;
    const bf16_t *Arow, *Brow;
    int m0, n0 = 0, b = 0, c0 = 0;
    if (id < 1024) {
        n0 = (id & 15) * 64; m0 = ((id >> 4) & 7) * 64; b = id >> 7;
        Arow = Wcat + (size_t)m0 * 384;
        Brow = xcat + ((size_t)b * 1024 + n0) * 384;
    } else {
        int g = id - 1024;
        m0 = (g & 127) * 64; c0 = (g >> 7) * 64;
        Arow = xcat + (size_t)m0 * 384;
        Brow = whhc + (size_t)c0 * 384;
    }

    f32x4 acc[4] = {};
    for (int k0 = 0; k0 < 384; k0 += 64) {
        STAGE64(As, Bs, Arow, Brow, 384, 384, k0, w, lane);
        __syncthreads();
        MFMA64(As, Bs, acc, w, lane);
        __syncthreads();
    }
    if (id < 1024) {
        #pragma unroll
        for (int j = 0; j < 4; ++j) {
            int n = n0 + j*16 + (lane & 15);
            #pragma unroll
            for (int rg = 0; rg < 4; ++rg) {
                int m = m0 + w*16 + (lane >> 4)*4 + rg;
                float v = acc[j][rg];
                if (m < 384) {
                    int d = m >> 7, o = m & 127;
                    supt[((size_t)((d*8 + b)*128 + o))*1024 + n] = (bf16_t)(v + Bcl[d*128 + o]);
                } else {
                    int o = m - 384;
                    tbuf[((size_t)(b*128 + o))*1024 + n] = fmaxf(v + Bhl[o], 0.0f);
                }
            }
        }
    } else {
        #pragma unroll
        for (int j = 0; j < 4; ++j) {
            int c = c0 + j*16 + (lane & 15);
            float bv = bhh[c];
            #pragma unroll
            for (int rg = 0; rg < 4; ++rg) {
                int m = m0 + w*16 + (lane >> 4)*4 + rg;
                ghb[(size_t)m*G3 + c] = (bf16_t)(acc[j][rg] + bv);
            }
        }
    }
}

// ---------------------------------------------------------------------------
// k_agg (64m x 128o per block, BK=64):
//   agg[z][m][o] = sum_n adjc[z][m][n]*supt[z][o][n] + 0.5*colsum[z][o]
// colsum analytic from xsum (fp32 exact). Output aggcat [24576][384] hi/lo-cat.
// grid (16 m-tiles, 24 z).
// ---------------------------------------------------------------------------
__global__ __launch_bounds__(256, 4) void k_agg(
    const bf16_t* __restrict__ adjb,   // [24][1024][1024] centered
    const bf16_t* __restrict__ supt,   // [24][128][1024]
    const float* __restrict__ xsum,    // [8][128] (this layer)
    const float* __restrict__ Wl,      // [3][128][128] fp32 (this layer)
    const float* __restrict__ Bcl,     // [3][128]
    bf16_t* __restrict__ aggcat)       // [24576][384]
{
    __shared__ bf16_t As[64*64];       // 8 KB
    __shared__ bf16_t Bs[128*64];      // 16 KB
    __shared__ float xs[128];
    __shared__ float red[256];
    __shared__ float cs_sh[128];
    const int t = threadIdx.x, lane = t & 63, w = t >> 6;
    const int m0 = blockIdx.x * 64;
    const int z  = blockIdx.y;
    const int b  = z & 7, d = z >> 3;

    if (t < 128) xs[t] = xsum[b*128 + t];
    __syncthreads();
    {
        int o = t & 127, h = t >> 7;
        float s = 0.0f;
        const float* Wd = Wl + (size_t)d*128*128;
        for (int k = h*64; k < h*64 + 64; ++k)
            s += xs[k] * Wd[k*128 + o];
        red[t] = s;
        __syncthreads();
        if (t < 128)
            cs_sh[t] = 0.5f*(red[t] + red[t+128]) + 512.0f*Bcl[d*128 + t];
        __syncthreads();
    }

    const bf16_t* Az = adjb + (size_t)z*1024*1024 + (size_t)m0*1024;
    const bf16_t* Bz = supt + (size_t)z*128*1024;

    f32x4 acc[8] = {};
    for (int k0 = 0; k0 < 1024; k0 += 64) {
        #pragma unroll
        for (int q = 0; q < 6; ++q) {
            int c = w*6 + q;                       // 24 chunks of 8 rows
            int rl = (lane >> 3), seg = (lane & 7)*8;
            if (c < 8)
                GLOAD_LDS16(Az + (size_t)(c*8 + rl)*1024 + k0 + seg,
                            (char*)As + c*1024);
            else
                GLOAD_LDS16(Bz + (size_t)((c-8)*8 + rl)*1024 + k0 + seg,
                            (char*)Bs + (c-8)*1024);
        }
        __syncthreads();
        #pragma unroll
        for (int ks = 0; ks < 64; ks += 32) {
            bf16x8 af = *reinterpret_cast<const bf16x8*>(
                &As[(w*16 + (lane & 15))*64 + ks + ((lane >> 4)*8)]);
            #pragma unroll
            for (int j = 0; j < 8; ++j) {
                bf16x8 bfv = *reinterpret_cast<const bf16x8*>(
                    &Bs[(j*16 + (lane & 15))*64 + ks + ((lane >> 4)*8)]);
                acc[j] = __builtin_amdgcn_mfma_f32_16x16x32_bf16(af, bfv, acc[j], 0, 0, 0);
            }
        }
        __syncthreads();
    }
    #pragma unroll
    for (int j = 0; j < 8; ++j) {
        int o = j*16 + (lane & 15);
        float cs = cs_sh[o];
        #pragma unroll
        for (int rg = 0; rg < 4; ++rg) {
            size_t m = (size_t)z*1024 + m0 + w*16 + (lane >> 4)*4 + rg;
            float v = acc[j][rg] + cs;
            bf16_t hi = (bf16_t)v;
            bf16_t lo = (bf16_t)(v - (float)hi);
            bf16_t* row = aggcat + m*384;
            row[o] = hi; row[128 + o] = lo; row[256 + o] = hi;
        }
    }
}

// ---------------------------------------------------------------------------
// FUSED gi GEMM + GRU gates + highway. Block = (16-n tile, b): 512 blocks.
// Phase 1: gi rows for this block's 48 (d,n) pairs (padded to 64) x 384 c,
//   K'=384 hi/lo exact: A = aggcat rows ((d*8+b)*1024+n), B = wihc (staged
//   fully per K-iter: 48 KB). Wave w = d (wave 3 pads/idles in MFMA).
// Phase 2: gi -> LDS in old girz(bf16)/gin(fp32) precisions (bit-identical),
//   then gates epilogue. LDS union 57.9 KB -> 2 blocks/CU.
// ---------------------------------------------------------------------------
__global__ __launch_bounds__(256, 2) void k_gigates(
    const bf16_t* __restrict__ aggcat, // [24576][384]
    const bf16_t* __restrict__ wihc,   // [384][384] (this layer)
    const float* __restrict__ bih,     // [384]
    const bf16_t* __restrict__ ghb,    // [8192][384]
    bf16_t* xcat,                      // NOT restrict: read+write same buffer
    const float* __restrict__ tbuf,    // [8][128][1024]
    float* __restrict__ Xout, int write_xcat,
    float* __restrict__ xsum_next)
{
    __shared__ char smem[58880];
    bf16_t* As  = (bf16_t*)smem;             // phase1 [64][64]      (8 KB)
    bf16_t* Bs  = (bf16_t*)(smem + 8192);    // phase1 [384][64]     (48 KB)
    bf16_t* rz  = (bf16_t*)smem;             // phase2 [3*16][256]   (24 KB)
    float*  gn  = (float*)(smem + 24576);    // phase2 [3*16][128]   (24 KB)
    float*  ts  = (float*)(smem + 49152);    // phase2 [128][17]     (8.7 KB)
    float*  red = (float*)(smem + 57856);    // phase2 [256]         (1 KB)
    const int t = threadIdx.x, lane = t & 63, w = t >> 6;
    const int n0 = blockIdx.x * 16, b = blockIdx.y;

    f32x4 acc[6][4] = {};
    for (int k0 = 0; k0 < 384; k0 += 64) {
        // stage 56 chunks (8 A + 48 B), 14 per wave
        #pragma unroll
        for (int q = 0; q < 14; ++q) {
            int c = w*14 + q;
            int rl = lane >> 3, seg = (lane & 7)*8;
            if (c < 8) {
                int r = c*8 + rl;                 // local A row 0..63
                int d = r >> 4; if (d > 2) d = 0; // pad rows -> d0 (ignored)
                int nn = r & 15;
                GLOAD_LDS16(aggcat + ((size_t)((d*8 + b)*1024) + n0 + nn)*384 + k0 + seg,
                            (char*)As + c*1024);
            } else {
                int r = (c - 8)*8 + rl;           // wihc row 0..383
                GLOAD_LDS16(wihc + (size_t)r*384 + k0 + seg,
                            (char*)Bs + (c - 8)*1024);
            }
        }
        __syncthreads();
        if (w < 3) {
            #pragma unroll
            for (int ks = 0; ks < 64; ks += 32) {
                bf16x8 af = *reinterpret_cast<const bf16x8*>(
                    &As[(w*16 + (lane & 15))*64 + ks + ((lane >> 4)*8)]);
                #pragma unroll
                for (int ct = 0; ct < 6; ++ct)
                    #pragma unroll
                    for (int j = 0; j < 4; ++j) {
                        bf16x8 bfv = *reinterpret_cast<const bf16x8*>(
                            &Bs[(ct*64 + j*16 + (lane & 15))*64 + ks + ((lane >> 4)*8)]);
                        acc[ct][j] = __builtin_amdgcn_mfma_f32_16x16x32_bf16(af, bfv, acc[ct][j], 0, 0, 0);
                    }
            }
        }
        __syncthreads();
    }
    // phase 2: gi -> LDS (old girz/gin precisions), stage t-tile, gates
    if (w < 3) {
        #pragma unroll
        for (int ct = 0; ct < 6; ++ct)
            #pragma unroll
            for (int j = 0; j < 4; ++j) {
                int c = ct*64 + j*16 + (lane & 15);
                float bv = bih[c];
                #pragma unroll
                for (int rg = 0; rg < 4; ++rg) {
                    int nn = (lane >> 4)*4 + rg;
                    float v = acc[ct][j][rg] + bv;
                    if (c < 256) rz[(w*16 + nn)*256 + c] = (bf16_t)v;
                    else         gn[(w*16 + nn)*128 + (c - 256)] = v;
                }
            }
    }
    {
        int o = t >> 1, nh = (t & 1) * 8;
        const float* src = tbuf + ((size_t)(b*128 + o))*1024 + n0 + nh;
        float4 v0 = *reinterpret_cast<const float4*>(src);
        float4 v1 = *reinterpret_cast<const float4*>(src + 4);
        float* dst = &ts[o*17 + nh];
        dst[0]=v0.x; dst[1]=v0.y; dst[2]=v0.z; dst[3]=v0.w;
        dst[4]=v1.x; dst[5]=v1.y; dst[6]=v1.z; dst[7]=v1.w;
    }
    __syncthreads();
    float xacc = 0.0f;
    #pragma unroll
    for (int p = 0; p < 8; ++p) {
        int e = p*256 + t;
        int nn = e >> 7, o = e & 127;
        int n = n0 + nn;
        size_t rb = (size_t)(b*1024 + n);
        bf16_t* xr = xcat + rb*384;
        float h = (float)xr[o] + (float)xr[256 + o];
        const bf16_t* ghr = ghb + rb*G3;
        float g_r = (float)ghr[o], g_z = (float)ghr[128+o], g_n = (float)ghr[256+o];
        float a2 = 0.0f;
        #pragma unroll
        for (int d = 0; d < 3; ++d) {
            float i_r = (float)rz[(d*16 + nn)*256 + o];
            float i_z = (float)rz[(d*16 + nn)*256 + 128 + o];
            float i_n = gn[(d*16 + nn)*128 + o];
            float rg = 1.0f / (1.0f + expf(-(i_r + g_r)));
            float zg = 1.0f / (1.0f + expf(-(i_z + g_z)));
            float ng = tanhf(i_n + rg * g_n);
            a2 += (1.0f - zg) * ng + zg * h;
        }
        float outv = fmaxf(a2, 0.0f);
        float tg = ts[o*17 + nn];
        float res = outv * tg + h * (1.0f - tg);
        xacc += res;
        if (Xout) Xout[(size_t)(n*8 + b)*128 + o] = res;
        if (write_xcat) {
            bf16_t hi = (bf16_t)res;
            bf16_t lo = (bf16_t)(res - (float)hi);
            xr[o] = hi; xr[128 + o] = hi; xr[256 + o] = lo;
        }
    }
    if (xsum_next) {
        red[t] = xacc;
        __syncthreads();
        if (t < 128)
            atomicAdd(xsum_next + b*128 + t, red[t] + red[t + 128]);
    }
}

// ---------------------------------------------------------------------------
extern "C" void kernel_launch(void* const* d_in, const int* in_sizes, int n_in,
                              void* d_out, int out_size, void* d_ws, size_t ws_size,
                              hipStream_t stream) {
    const float* inputs = (const float*)d_in[0];   // [1024,8,128]
    const float* adj    = (const float*)d_in[1];   // [3,8,1024,1024]
    const float* W      = (const float*)d_in[2];   // [2,3,128,128]
    const float* Bc     = (const float*)d_in[3];   // [2,3,128]
    const float* Wh     = (const float*)d_in[4];   // [2,128,128]
    const float* Bh     = (const float*)d_in[5];   // [2,128]
    const float* Wih    = (const float*)d_in[6];   // [2,384,128]
    const float* Whh    = (const float*)d_in[7];   // [2,384,128]
    const float* bih    = (const float*)d_in[8];   // [2,384]
    const float* bhh    = (const float*)d_in[9];   // [2,384]

    char* ws = (char*)d_ws;
    float*  tbuf   = (float*)ws;   ws += (size_t)8*128*1024*4;      // 4.19 MB
    bf16_t* xcat   = (bf16_t*)ws;  ws += (size_t)8*1024*384*2;      // 6.29 MB
    bf16_t* ghb    = (bf16_t*)ws;  ws += (size_t)NB*G3*2;           // 6.29 MB
    bf16_t* supt   = (bf16_t*)ws;  ws += (size_t)24*128*1024*2;     // 6.29 MB
    bf16_t* aggcat = (bf16_t*)ws;  ws += (size_t)3*NB*384*2;        // 18.87 MB
    float*  xsum   = (float*)ws;   ws += (size_t)2*8*128*4;         // 8 KB
    bf16_t* wsup   = (bf16_t*)ws;  ws += (size_t)2*512*384*2;       // 0.79 MB
    bf16_t* whhc   = (bf16_t*)ws;  ws += (size_t)2*384*384*2;       // 1.18 MB
    bf16_t* wihc   = (bf16_t*)ws;  ws += (size_t)2*384*384*2;       // 1.18 MB
    bf16_t* adjb   = (bf16_t*)ws;                                   // 50.33 MB

    // one-time preps
    hipMemsetAsync(xsum, 0, 2*8*128*sizeof(float), stream);
    k_cvt_adj<<<dim3(4096), dim3(256), 0, stream>>>(adj, adjb, 3*8*1024*1024/4);
    k_wprep<<<dim3(1280, 2), dim3(128), 0, stream>>>(W, Wh, Whh, Wih, wsup, whhc, wihc);
    k_xcat<<<dim3(4096), dim3(256), 0, stream>>>(inputs, xcat);
    k_xsum0<<<dim3(64, 8), dim3(256), 0, stream>>>(inputs, xsum);

    for (int l = 0; l < 2; ++l) {
        // fused: support (bf16 [z][o][n]) + highway t (fp32 [b][o][n]) + gh
        k_supgh<<<dim3(1792), dim3(256), 0, stream>>>(
            wsup + (size_t)l*512*384, xcat, whhc + (size_t)l*384*384,
            Bc + l*3*128, Bh + l*128, bhh + l*G3, supt, tbuf, ghb);
        // agg = adjc @ support + 0.5*colsum(analytic), output hi/lo-cat
        k_agg<<<dim3(16, 24), dim3(256), 0, stream>>>(
            adjb, supt, xsum + l*1024, W + (size_t)l*3*128*128, Bc + l*3*128,
            aggcat);
        // fused gi GEMM + gates + highway; layer0 -> xcat update + xsum1 accum
        k_gigates<<<dim3(64, 8), dim3(256), 0, stream>>>(
            aggcat, wihc + (size_t)l*384*384, bih + l*G3, ghb, xcat, tbuf,
            (l == 1) ? (float*)d_out : (float*)nullptr, (l == 0) ? 1 : 0,
            (l == 0) ? (xsum + 1024) : (float*)nullptr);
    }
}